// Round 2
// baseline (188.686 us; speedup 1.0000x reference)
//
#include <hip/hip_runtime.h>

#define NCLS 80
#define BATCH 32
#define N0 (BATCH * 80 * 80)   // 204800
#define N1 (BATCH * 40 * 40)   // 51200
#define N2 (BATCH * 20 * 20)   // 12800
#define NCELL (N0 + N1 + N2)   // 268800 (all boundaries multiples of 64)
#define NBLK 1024
#define TPB 256

// Per-block partials: [0..2]=lbox_s, [3..5]=lcls_s, [6..8]=cnt, [9..11]=lobj_s
// Written unconditionally by every block every call -> no zero-init needed.
__device__ float g_part[NBLK * 12];

__device__ __forceinline__ float sigmoid_f(float x) {
    return 1.0f / (1.0f + expf(-x));
}

__device__ __forceinline__ float softplus_f(float x) {
    // stable: max(x,0) + log1p(exp(-|x|))
    return fmaxf(x, 0.0f) + log1pf(expf(-fabsf(x)));
}

__device__ float ciou_f(float px, float py, float pw, float ph,
                        float tx, float ty, float tw, float th) {
    const float eps = 1e-7f;
    float b1x1 = px - pw * 0.5f, b1x2 = px + pw * 0.5f;
    float b1y1 = py - ph * 0.5f, b1y2 = py + ph * 0.5f;
    float b2x1 = tx - tw * 0.5f, b2x2 = tx + tw * 0.5f;
    float b2y1 = ty - th * 0.5f, b2y2 = ty + th * 0.5f;
    float iw = fmaxf(fminf(b1x2, b2x2) - fmaxf(b1x1, b2x1), 0.0f);
    float ih = fmaxf(fminf(b1y2, b2y2) - fmaxf(b1y1, b2y1), 0.0f);
    float inter = iw * ih;
    float uni = pw * ph + tw * th - inter + eps;
    float iou = inter / uni;
    float cw = fmaxf(b1x2, b2x2) - fminf(b1x1, b2x1);
    float ch = fmaxf(b1y2, b2y2) - fminf(b1y1, b2y1);
    float c2 = cw * cw + ch * ch + eps;
    float dx = b2x1 + b2x2 - b1x1 - b1x2;
    float dy = b2y1 + b2y2 - b1y1 - b1y2;
    float rho2 = (dx * dx + dy * dy) * 0.25f;
    float dat = atanf(tw / th) - atanf(pw / ph);
    const float k = 0.40528473456935108577551785f; // 4/pi^2
    float v = k * dat * dat;
    float alpha = v / (v - iou + (1.0f + eps));
    return iou - (rho2 / c2 + v * alpha);
}

__global__ __launch_bounds__(TPB) void main_kernel(
        const float* __restrict__ p0,
        const float* __restrict__ p1,
        const float* __restrict__ p2,
        const float* __restrict__ tg, int nt) {
    __shared__ float sh[12];
    int tid = threadIdx.x;
    if (tid < 12) sh[tid] = 0.0f;
    __syncthreads();

    int total = NCELL + 3 * nt;
    for (int base = blockIdx.x * TPB; base < total; base += NBLK * TPB) {
        int idx = base + tid;
        if (idx < NCELL) {
            // ---- cell path: lobj softplus term ----
            // All region boundaries (N0, N0+N1, NCELL) are multiples of 64,
            // and base is a multiple of 256, so each wave is level-uniform
            // and fully active here -> shuffle reduce is safe.
            int lvl, cell;
            const float* p;
            if (idx < N0)           { lvl = 0; cell = idx;           p = p0; }
            else if (idx < N0 + N1) { lvl = 1; cell = idx - N0;      p = p1; }
            else                    { lvl = 2; cell = idx - N0 - N1; p = p2; }
            float xo = p[(size_t)cell * (NCLS + 5) + 4];
            float v = softplus_f(xo);
            #pragma unroll
            for (int off = 32; off > 0; off >>= 1)
                v += __shfl_down(v, off, 64);
            if ((tid & 63) == 0) atomicAdd(&sh[9 + lvl], v);
        } else if (idx < total) {
            // ---- target path ----
            int id = idx - NCELL;
            int lvl = id / nt;
            int t = id - lvl * nt;

            int W = (lvl == 0) ? 80 : ((lvl == 1) ? 40 : 20);
            float s = (lvl == 0) ? 8.0f : ((lvl == 1) ? 16.0f : 32.0f);
            const float* p = (lvl == 0) ? p0 : ((lvl == 1) ? p1 : p2);

            const float* row = tg + t * 6;
            float bf = row[0], cf = row[1];
            float x = row[2], y = row[3], w = row[4], h = row[5];

            float Wf = (float)W;
            float gw = w * Wf, gh = h * Wf;   // gain (H == W per level)
            float rw = gw / s, rh = gh / s;
            float m = fmaxf(fmaxf(rw, 1.0f / rw), fmaxf(rh, 1.0f / rh));
            if (m < 4.0f) {                   // keep filter
                float gx = x * Wf, gy = y * Wf;
                int b = (int)bf;
                int c = (int)cf;

                // offset candidates; jj/ll and kk/mm are mutually exclusive,
                // so ne <= 3. Order irrelevant (all consumers are means /
                // near-collision-free scatter).
                float ox[3], oy[3];
                int ne = 0;
                ox[ne] = 0.0f; oy[ne] = 0.0f; ne++;
                bool jj = (fmodf(gx, 1.0f) < 0.5f) && (gx > 1.0f);
                bool kk = (fmodf(gy, 1.0f) < 0.5f) && (gy > 1.0f);
                float gxi = Wf - gx, gyi = Wf - gy;
                bool ll = (fmodf(gxi, 1.0f) < 0.5f) && (gxi > 1.0f);
                bool mm = (fmodf(gyi, 1.0f) < 0.5f) && (gyi > 1.0f);
                if (jj) { ox[ne] = 0.5f;  oy[ne] = 0.0f;  ne++; }
                if (ll) { ox[ne] = -0.5f; oy[ne] = 0.0f;  ne++; }
                if (kk) { ox[ne] = 0.0f;  oy[ne] = 0.5f;  ne++; }
                if (mm) { ox[ne] = 0.0f;  oy[ne] = -0.5f; ne++; }

                float lbox_acc = 0.0f, lcls_acc = 0.0f, lobj_sub = 0.0f;
                for (int e = 0; e < ne; e++) {
                    int gi = (int)(gx - ox[e]);  // operands > 0: trunc == floor
                    int gj = (int)(gy - oy[e]);
                    gi = min(max(gi, 0), W - 1);
                    gj = min(max(gj, 0), W - 1);
                    int cell = (b * W + gj) * W + gi;  // a == 0
                    const float* pr = p + (size_t)cell * (NCLS + 5);

                    float px = sigmoid_f(pr[0]) * 2.0f - 0.5f;
                    float py = sigmoid_f(pr[1]) * 2.0f - 0.5f;
                    float sw = sigmoid_f(pr[2]) * 2.0f;
                    float shh = sigmoid_f(pr[3]) * 2.0f;
                    float pw = sw * sw * s;
                    float ph = shh * shh * s;

                    float tbx = gx - (float)gi;
                    float tby = gy - (float)gj;

                    float iou = ciou_f(px, py, pw, ph, tbx, tby, gw, gh);
                    lbox_acc += 1.0f - iou;
                    lobj_sub += pr[4] * fmaxf(iou, 0.0f);  // x4 * tobj scatter term

                    float cs = 0.0f;
                    #pragma unroll 4
                    for (int kci = 0; kci < NCLS; kci++)
                        cs += softplus_f(pr[5 + kci]);
                    cs -= pr[5 + c];  // minus x at the one-hot class
                    lcls_acc += cs;
                }
                atomicAdd(&sh[lvl], lbox_acc);
                atomicAdd(&sh[3 + lvl], lcls_acc);
                atomicAdd(&sh[6 + lvl], (float)ne);
                atomicAdd(&sh[9 + lvl], -lobj_sub);
            }
        }
    }
    __syncthreads();
    if (tid < 12) g_part[blockIdx.x * 12 + tid] = sh[tid];
}

__global__ __launch_bounds__(TPB) void reduce_kernel(float* __restrict__ out) {
    __shared__ float red[12][TPB];
    int tid = threadIdx.x;
    float loc[12];
    #pragma unroll
    for (int c = 0; c < 12; c++) loc[c] = 0.0f;
    for (int b = tid; b < NBLK; b += TPB) {
        #pragma unroll
        for (int c = 0; c < 12; c++) loc[c] += g_part[b * 12 + c];
    }
    #pragma unroll
    for (int c = 0; c < 12; c++) red[c][tid] = loc[c];
    __syncthreads();
    for (int st = TPB / 2; st > 0; st >>= 1) {
        if (tid < st) {
            #pragma unroll
            for (int c = 0; c < 12; c++) red[c][tid] += red[c][tid + st];
        }
        __syncthreads();
    }
    if (tid == 0) {
        const float BAL[3] = {4.0f, 1.0f, 0.4f};
        const float NCF[3] = {(float)N0, (float)N1, (float)N2};
        float lbox = 0.0f, lcls = 0.0f, lobj = 0.0f;
        for (int l = 0; l < 3; l++) {
            float n = red[6 + l][0];
            if (n > 0.5f) {
                lbox += red[l][0] / n;
                lcls += red[3 + l][0] / (n * (float)NCLS);
            }
            lobj += red[9 + l][0] / NCF[l] * BAL[l];
        }
        lbox *= 7.5f;  // BOX_W
        lcls *= 0.5f;  // CLS_W
        float loss = (lbox + lobj + lcls) * (float)BATCH;
        out[0] = loss;
        out[1] = lbox;
        out[2] = lobj;
        out[3] = lcls;
    }
}

extern "C" void kernel_launch(void* const* d_in, const int* in_sizes, int n_in,
                              void* d_out, int out_size, void* d_ws, size_t ws_size,
                              hipStream_t stream) {
    const float* p0 = (const float*)d_in[0];
    const float* p1 = (const float*)d_in[1];
    const float* p2 = (const float*)d_in[2];
    const float* tg = (const float*)d_in[3];
    int nt = in_sizes[3] / 6;
    float* out = (float*)d_out;

    main_kernel<<<NBLK, TPB, 0, stream>>>(p0, p1, p2, tg, nt);
    reduce_kernel<<<1, TPB, 0, stream>>>(out);
}